// Round 3
// baseline (1370.428 us; speedup 1.0000x reference)
//
#include <hip/hip_runtime.h>
#include <hip/hip_bf16.h>

typedef __attribute__((ext_vector_type(8))) short s8v;
typedef __attribute__((ext_vector_type(4))) float f4v;
typedef __attribute__((ext_vector_type(4))) unsigned int u4v;
typedef __attribute__((ext_vector_type(2))) unsigned int u2v;

#define BATCH 32
#define SEQ   2048
#define DIM   256
#define ORIGIN_OFF ((size_t)BATCH * SEQ * DIM)

// ---- workspace layout (units: bf16 shorts) ----
// xT  [32][256][2048]  : x transposed per batch, bf16
// wlT [2048 q][256 k]  : wl_w^T bf16
// hisT[256 n][256 k]   : his_w^T bf16
// mlpT[256 n][256 k]   : mlp_w^T bf16
#define XT_OFF  0ull
#define WL_OFF  16777216ull
#define HIS_OFF 17301504ull
#define MLP_OFF 17367040ull

// ---- LDS layout (bytes), total 46336 (3 blocks/CU) ----
// flash : sK  @ 0      [64 q][512B] linear + XOR-swizzled chunks (32768)
//         sP  @ 33792  [64 p][144B] (9216)
//         statm @ 43008 (512), stats @ 43520 (512)
// prolog: sQ  @ 0      [64 rows][264 sh] stride 528 (33792)
// epilog: agg @ 0      (33792)  [sP/stats dead]
//         cg @ 43008 (1024), cb @ 44032, wp/wcS @ 44048 (1024),
//         Ls @ 45072 (512), Lq @ 45584 (512)
#define OFF_SP   33792
#define OFF_SM   43008
#define OFF_SS   43520
#define EP_CG    43008
#define EP_CB    44032
#define EP_WP    44048
#define EP_LS    45072
#define EP_LQ    45584

__device__ __forceinline__ unsigned short f2bf(float f) {
  __hip_bfloat16 h = __float2bfloat16(f);   // round-to-nearest-even
  return *reinterpret_cast<unsigned short*>(&h);
}
__device__ __forceinline__ f4v mfma16(s8v a, s8v b, f4v c) {
  return __builtin_amdgcn_mfma_f32_16x16x32_bf16(a, b, c, 0, 0, 0);
}
__device__ __forceinline__ unsigned int pk2(float lo, float hi) {
  return (unsigned int)f2bf(lo) | ((unsigned int)f2bf(hi) << 16);
}
// async global->LDS, 16B per lane; LDS dest = wave-uniform base + lane*16
__device__ __forceinline__ void dma16(const void* g, void* l) {
  __builtin_amdgcn_global_load_lds(
      (const __attribute__((address_space(1))) unsigned int*)g,
      (__attribute__((address_space(3))) unsigned int*)l, 16, 0, 0);
}

// ---------------- unified prep kernel ----------------
// 64x64 tile transpose f32 -> bf16 via LDS, chunk-XOR-swizzled (conflict-free).
// grid.x = 4096 (xT tiles) + 128 (wl) + 16 (his) + 16 (mlp) = 4256
__global__ __launch_bounds__(256) void prep_all(
    const float* __restrict__ x, const float* __restrict__ wl_w,
    const float* __restrict__ his_w, const float* __restrict__ mlp_w,
    unsigned short* __restrict__ ws)
{
  __shared__ unsigned short tile[64][72];   // 144B stride
  const int t = threadIdx.x;
  const int tb = blockIdx.x;
  const float* src; unsigned short* dst; int lds_, ldd_, r0, c0;
  if (tb < 4096) {
    const int b = tb >> 7, rem = tb & 127;
    r0 = (rem >> 2) * 64;  c0 = (rem & 3) * 64;
    src = x + (size_t)b * SEQ * DIM;  lds_ = DIM;
    dst = ws + XT_OFF + (size_t)b * DIM * SEQ;  ldd_ = SEQ;
  } else if (tb < 4224) {
    const int t2 = tb - 4096;
    r0 = (t2 >> 5) * 64;  c0 = (t2 & 31) * 64;
    src = wl_w;  lds_ = 2048;  dst = ws + WL_OFF;  ldd_ = 256;
  } else if (tb < 4240) {
    const int t2 = tb - 4224;
    r0 = (t2 >> 2) * 64;  c0 = (t2 & 3) * 64;
    src = his_w;  lds_ = 256;  dst = ws + HIS_OFF;  ldd_ = 256;
  } else {
    const int t2 = tb - 4240;
    r0 = (t2 >> 2) * 64;  c0 = (t2 & 3) * 64;
    src = mlp_w;  lds_ = 256;  dst = ws + MLP_OFF;  ldd_ = 256;
  }
  { // phase 1: read rows coalesced, store 16B chunks at slot ch^(rr>>4)
    const int rr = t >> 2, cc = (t & 3) * 16;
    const float* s0 = src + (size_t)(r0 + rr) * lds_ + c0 + cc;
    f4v v0 = *(const f4v*)(s0);
    f4v v1 = *(const f4v*)(s0 + 4);
    f4v v2 = *(const f4v*)(s0 + 8);
    f4v v3 = *(const f4v*)(s0 + 12);
    u4v o0, o1;
    o0[0] = pk2(v0[0], v0[1]); o0[1] = pk2(v0[2], v0[3]);
    o0[2] = pk2(v1[0], v1[1]); o0[3] = pk2(v1[2], v1[3]);
    o1[0] = pk2(v2[0], v2[1]); o1[1] = pk2(v2[2], v2[3]);
    o1[2] = pk2(v3[0], v3[1]); o1[3] = pk2(v3[2], v3[3]);
    const int swz = rr >> 4;
    const int ch = cc >> 3;          // 0,2,4,6
    unsigned short* trow = &tile[rr][0];
    *(u4v*)(trow + ((ch ^ swz) << 3)) = o0;
    *(u4v*)(trow + (((ch + 1) ^ swz) << 3)) = o1;
  }
  __syncthreads();
  { // phase 2: column reads (swizzle undone), coalesced transposed store
    const int cl = t >> 2, sg = t & 3;     // output row cl, source rows sg*16..
    const int chb = ((cl >> 3) ^ sg) << 3; // row>>4 == sg for all 16 rows
    const int el = cl & 7;
    u4v o0, o1;
    #pragma unroll
    for (int j = 0; j < 4; ++j) {
      const int rA = sg * 16 + 2 * j;
      o0[j] = (unsigned int)tile[rA][chb + el]
            | ((unsigned int)tile[rA + 1][chb + el] << 16);
    }
    #pragma unroll
    for (int j = 0; j < 4; ++j) {
      const int rA = sg * 16 + 8 + 2 * j;
      o1[j] = (unsigned int)tile[rA][chb + el]
            | ((unsigned int)tile[rA + 1][chb + el] << 16);
    }
    unsigned short* d0 = dst + (size_t)(c0 + cl) * ldd_ + r0 + sg * 16;
    *(u4v*)d0 = o0;
    *(u4v*)(d0 + 8) = o1;
  }
}

// ---------------- main kernel ----------------

// acc[a][i] += A(regs af) @ Wt(bf16 [n 256][k 256] row-major), B-frags
// direct from global (L2).  n = (i>>1)*64 + wc*32 + (i&1)*16 + col16.
__device__ __forceinline__ void gemm_direct(
    const unsigned short* __restrict__ Wt,
    const s8v (&af)[2][8], f4v (&acc)[2][8], int col16, int quad, int wc)
{
  #pragma unroll
  for (int i = 0; i < 8; ++i) {
    const int n = (i >> 1) * 64 + wc * 32 + (i & 1) * 16 + col16;
    const unsigned short* bp = Wt + (size_t)n * 256 + quad * 8;
    #pragma unroll
    for (int s = 0; s < 8; ++s) {
      s8v bfr = *(const s8v*)(bp + s * 32);
      acc[0][i] = mfma16(af[0][s], bfr, acc[0][i]);
      acc[1][i] = mfma16(af[1][s], bfr, acc[1][i]);
    }
  }
}

__global__ __launch_bounds__(256, 3)
void tfs_kernel(
    const float* __restrict__ x,
    const float* __restrict__ mlp_b,
    const float* __restrict__ his_b,
    const float* __restrict__ cur_w,
    const float* __restrict__ cur_b,
    const float* __restrict__ wl_b,
    const float* __restrict__ gate_w,
    const float* __restrict__ gate_b,
    const float* __restrict__ ln_g,
    const float* __restrict__ ln_b,
    const unsigned short* __restrict__ wsp,
    float* __restrict__ out)
{
  __shared__ __align__(16) char smem[46336];

  const int tid = threadIdx.x;
  const int lane = tid & 63;
  const int col16 = lane & 15;
  const int quad = lane >> 4;
  const int w = tid >> 6;
  const int wr = w & 1, wc = w >> 1;
  const int rw = wr * 32;
  const int x7 = col16 & 7;
  const int wq = __builtin_amdgcn_readfirstlane(w);

  // load-balance remap: rotate bx so consecutive blocks get pidx spaced by 8
  const int b = blockIdx.y;
  const int bx = blockIdx.x;
  const int pidx = ((((bx & 3) << 3) | (bx >> 2)) + b) & 31;
  const int p0 = pidx * 64;

  const float* xb = x + (size_t)b * SEQ * DIM;
  const unsigned short* wlT  = wsp + WL_OFF;
  const unsigned short* hisT = wsp + HIS_OFF;
  const unsigned short* mlpT = wsp + MLP_OFF;
  const unsigned short* xTb  = wsp + XT_OFF + (size_t)b * DIM * SEQ;
  const f4v zero4 = {0.f, 0.f, 0.f, 0.f};

  // sK DMA lane roles (pre-swizzled source chunks, linear LDS dest)
  const int krow = tid >> 5;                // 0..7
  const int ku   = (tid & 31) ^ krow;       // chunk within 512B row
  char* ldsK = smem + wq * 1024;
  char* sP = smem + OFF_SP;
  float* stat_max = (float*)(smem + OFF_SM);   // [2][64]
  float* stat_sum = (float*)(smem + OFF_SS);   // [2][64]

  // ---- x fragments direct from global (f32 -> bf16 pack) ----
  s8v xf[2][8];
  #pragma unroll
  for (int a = 0; a < 2; ++a) {
    const int row = rw + a * 16 + col16;
    const float* srcx = xb + (size_t)(p0 + row) * DIM;
    #pragma unroll
    for (int s = 0; s < 8; ++s) {
      const int k0 = (s * 4 + quad) * 8;
      f4v v0 = *(const f4v*)(srcx + k0);
      f4v v1 = *(const f4v*)(srcx + k0 + 4);
      u4v o;
      o[0] = pk2(v0[0], v0[1]); o[1] = pk2(v0[2], v0[3]);
      o[2] = pk2(v1[0], v1[1]); o[3] = pk2(v1[2], v1[3]);
      xf[a][s] = *(s8v*)&o;
    }
  }

  // ---- Q = x @ his_w + his_b (direct-global GEMM) ----
  f4v accQ[2][8];
  #pragma unroll
  for (int a = 0; a < 2; ++a)
    #pragma unroll
    for (int i = 0; i < 8; ++i) accQ[a][i] = zero4;
  gemm_direct(hisT, xf, accQ, col16, quad, wc);
  // writeback Q -> smem (stride 528) for fragment re-layout
  #pragma unroll
  for (int a = 0; a < 2; ++a)
    #pragma unroll
    for (int i = 0; i < 8; ++i) {
      const int n = (i >> 1) * 64 + wc * 32 + (i & 1) * 16 + col16;
      const float bias = his_b[n];
      #pragma unroll
      for (int r = 0; r < 4; ++r) {
        const int row = rw + a * 16 + quad * 4 + r;
        *(unsigned short*)(smem + row * 528 + n * 2) = f2bf(accQ[a][i][r] + bias);
      }
    }
  __syncthreads();                         // Q visible
  s8v qf[2][8];                            // qi-invariant Q fragments
  #pragma unroll
  for (int a = 0; a < 2; ++a) {
    const int row = rw + a * 16 + col16;
    #pragma unroll
    for (int s = 0; s < 8; ++s)
      qf[a][s] = *(const s8v*)(smem + row * 528 + (s * 4 + quad) * 16);
  }
  __syncthreads();                         // qf reads done; region free for sK
  { // stage sK(0)
    const unsigned short* srck = wlT + (size_t)krow * 256 + ku * 8;
    #pragma unroll
    for (int j = 0; j < 8; ++j) dma16(srck + (size_t)j * 2048, ldsK + j * 4096);
  }
  __syncthreads();                         // sK(0) ready (vmcnt(0) drain)

  // ---- flash loop ----
  f4v accO[2][8];
  #pragma unroll
  for (int a = 0; a < 2; ++a)
    #pragma unroll
    for (int dt = 0; dt < 8; ++dt) accO[a][dt] = zero4;
  float mrun[2][4], Zrun[2][4], mrunT[2];
  #pragma unroll
  for (int a = 0; a < 2; ++a) {
    mrunT[a] = -1.0e30f;
    #pragma unroll
    for (int r = 0; r < 4; ++r) { mrun[a][r] = -1.0e30f; Zrun[a][r] = 0.f; }
  }
  const int rk0 = (wc * 32 + col16) * 512;
  const int rk1 = rk0 + 16 * 512;

  #pragma unroll 1
  for (int qi = 0; qi < 32; ++qi) {
    const int q0 = qi * 64;
    const bool active = (q0 <= p0);

    // --- S^T = K @ Q ---
    f4v accST[2][2];
    accST[0][0] = zero4; accST[0][1] = zero4;
    accST[1][0] = zero4; accST[1][1] = zero4;
    #pragma unroll
    for (int s = 0; s < 8; ++s) {
      const int sl = (((s * 4 + quad) ^ x7) << 4);
      s8v kf0 = *(const s8v*)(smem + rk0 + sl);
      s8v kf1 = *(const s8v*)(smem + rk1 + sl);
      accST[0][0] = mfma16(kf0, qf[0][s], accST[0][0]);
      accST[0][1] = mfma16(kf0, qf[1][s], accST[0][1]);
      accST[1][0] = mfma16(kf1, qf[0][s], accST[1][0]);
      accST[1][1] = mfma16(kf1, qf[1][s], accST[1][1]);
    }
    // + wl_b
    #pragma unroll
    for (int t = 0; t < 2; ++t) {
      const f4v wb = *(const f4v*)(wl_b + q0 + wc * 32 + t * 16 + quad * 4);
      #pragma unroll
      for (int a = 0; a < 2; ++a)
        #pragma unroll
        for (int r = 0; r < 4; ++r) accST[t][a][r] += wb[r];
    }
    // tile row-max: in-lane over 8 + 2 shuffles
    #pragma unroll
    for (int a = 0; a < 2; ++a) {
      float m = fmaxf(fmaxf(fmaxf(accST[0][a][0], accST[0][a][1]),
                            fmaxf(accST[0][a][2], accST[0][a][3])),
                      fmaxf(fmaxf(accST[1][a][0], accST[1][a][1]),
                            fmaxf(accST[1][a][2], accST[1][a][3])));
      m = fmaxf(m, __shfl_xor(m, 16, 64));
      m = fmaxf(m, __shfl_xor(m, 32, 64));
      if (quad == 0) stat_max[wc * 64 + rw + a * 16 + col16] = m;
    }
    __syncthreads();                     // [B1] stats visible; sK reads drained

    if (qi < 31) {                       // prefetch sK(qi+1)
      const unsigned short* srck = wlT + (size_t)(q0 + 64 + krow) * 256 + ku * 8;
      #pragma unroll
      for (int j = 0; j < 8; ++j) dma16(srck + (size_t)j * 2048, ldsK + j * 4096);
    }
    s8v bv[2][8];                        // PV B-frags direct from L2
    if (active) {
      #pragma unroll
      for (int h = 0; h < 2; ++h)
        #pragma unroll
        for (int dt = 0; dt < 8; ++dt) {
          const int d = wc * 128 + dt * 16 + col16;
          bv[h][dt] = *(const s8v*)(xTb + (size_t)d * 2048 + q0 + (h * 4 + quad) * 8);
        }
    }

    // alpha for accO rows (PV mapping) + rescale-needed flag
    float alpha[2][4];
    int anyr = 0;
    #pragma unroll
    for (int a = 0; a < 2; ++a) {
      const f4v mlo = *(const f4v*)(stat_max + rw + a * 16 + quad * 4);
      const f4v mhi = *(const f4v*)(stat_max + 64 + rw + a * 16 + quad * 4);
      #pragma unroll
      for (int r = 0; r < 4; ++r) {
        const float mt = fmaxf(mlo[r], mhi[r]);
        const float mn = fmaxf(mrun[a][r], mt);
        anyr |= (mt > mrun[a][r]) ? 1 : 0;
        alpha[a][r] = __expf(fminf(mrun[a][r] - mn, 0.f));
        mrun[a][r] = mn;
      }
    }
    // running max in S^T mapping
    #pragma unroll
    for (int a = 0; a < 2; ++a) {
      const int p = rw + a * 16 + col16;
      mrunT[a] = fmaxf(mrunT[a], fmaxf(stat_max[p], stat_max[64 + p]));
    }
    // P = exp(S - m)
    float Pv[2][2][4];
    #pragma unroll
    for (int t = 0; t < 2; ++t)
      #pragma unroll
      for (int a = 0; a < 2; ++a)
        #pragma unroll
        for (int r = 0; r < 4; ++r)
          Pv[t][a][r] = __expf(fminf(accST[t][a][r] - mrunT[a], 0.f));
    // row sums
    #pragma unroll
    for (int a = 0; a < 2; ++a) {
      float s = ((Pv[0][a][0] + Pv[0][a][1]) + (Pv[0][a][2] + Pv[0][a][3]))
              + ((Pv[1][a][0] + Pv[1][a][1]) + (Pv[1][a][2] + Pv[1][a][3]));
      s += __shfl_xor(s, 16, 64);
      s += __shfl_xor(s, 32, 64);
      if (quad == 0) stat_sum[wc * 64 + rw + a * 16 + col16] = s;
    }
    // masked P -> sP (packed b64 writes: r contiguous in ql)
    if (active) {
      #pragma unroll
      for (int t = 0; t < 2; ++t)
        #pragma unroll
        for (int a = 0; a < 2; ++a) {
          const int p = rw + a * 16 + col16;
          const int ql0 = wc * 32 + t * 16 + quad * 4;
          const int lim = p0 + p - q0;   // keep ql <= lim
          const float v0 = (ql0 + 0 <= lim) ? Pv[t][a][0] : 0.f;
          const float v1 = (ql0 + 1 <= lim) ? Pv[t][a][1] : 0.f;
          const float v2 = (ql0 + 2 <= lim) ? Pv[t][a][2] : 0.f;
          const float v3 = (ql0 + 3 <= lim) ? Pv[t][a][3] : 0.f;
          u2v pk; pk[0] = pk2(v0, v1); pk[1] = pk2(v2, v3);
          *(u2v*)(sP + p * 144 + ql0 * 2) = pk;
        }
    }
    __syncthreads();                     // [B2] sP/stat_sum/sK(qi+1)/bv ready

    // Z update + conditional O rescale (wave-uniform skip when alpha==1)
    if (__any(anyr)) {
      #pragma unroll
      for (int a = 0; a < 2; ++a) {
        const f4v slo = *(const f4v*)(stat_sum + rw + a * 16 + quad * 4);
        const f4v shi = *(const f4v*)(stat_sum + 64 + rw + a * 16 + quad * 4);
        #pragma unroll
        for (int r = 0; r < 4; ++r)
          Zrun[a][r] = Zrun[a][r] * alpha[a][r] + (slo[r] + shi[r]);
      }
      #pragma unroll
      for (int a = 0; a < 2; ++a)
        #pragma unroll
        for (int dt = 0; dt < 8; ++dt)
          #pragma unroll
          for (int r = 0; r < 4; ++r) accO[a][dt][r] *= alpha[a][r];
    } else {
      #pragma unroll
      for (int a = 0; a < 2; ++a) {
        const f4v slo = *(const f4v*)(stat_sum + rw + a * 16 + quad * 4);
        const f4v shi = *(const f4v*)(stat_sum + 64 + rw + a * 16 + quad * 4);
        #pragma unroll
        for (int r = 0; r < 4; ++r) Zrun[a][r] += (slo[r] + shi[r]);
      }
    }

    if (active) {                        // PV
      #pragma unroll
      for (int h = 0; h < 2; ++h) {
        s8v ap0 = *(const s8v*)(sP + (rw + col16) * 144 + (h * 4 + quad) * 16);
        s8v ap1 = *(const s8v*)(sP + (rw + 16 + col16) * 144 + (h * 4 + quad) * 16);
        #pragma unroll
        for (int dt = 0; dt < 8; ++dt) {
          accO[0][dt] = mfma16(ap0, bv[h][dt], accO[0][dt]);
          accO[1][dt] = mfma16(ap1, bv[h][dt], accO[1][dt]);
        }
      }
    }
  } // qi

  // ---- epilogue: agg = O/Z -> smem (bf16, stride 528) ----
  #pragma unroll
  for (int a = 0; a < 2; ++a)
    #pragma unroll
    for (int dt = 0; dt < 8; ++dt) {
      const int d = wc * 128 + dt * 16 + col16;
      #pragma unroll
      for (int r = 0; r < 4; ++r) {
        const int row = rw + a * 16 + quad * 4 + r;
        const float invZ = 1.0f / fmaxf(Zrun[a][r], 1e-30f);
        *(unsigned short*)(smem + row * 528 + d * 2) = f2bf(accO[a][dt][r] * invZ);
      }
    }
  __syncthreads();                       // agg visible; all flash LDS dead
  s8v af[2][8];
  #pragma unroll
  for (int a = 0; a < 2; ++a) {
    const int row = rw + a * 16 + col16;
    #pragma unroll
    for (int s = 0; s < 8; ++s)
      af[a][s] = *(const s8v*)(smem + row * 528 + (s * 4 + quad) * 16);
  }
  // ---- H_hist = agg @ mlp_w (direct-global GEMM) ----
  f4v accH[2][8];
  #pragma unroll
  for (int a = 0; a < 2; ++a)
    #pragma unroll
    for (int i = 0; i < 8; ++i) accH[a][i] = zero4;
  gemm_direct(mlpT, af, accH, col16, quad, wc);

  // ---- cg[d] = cur_w[d,:]·gate_w ; cb  (region disjoint from af reads) ----
  float* cgL = (float*)(smem + EP_CG);
  float* cbL = (float*)(smem + EP_CB);
  {
    const float* cw = cur_w + (size_t)tid * DIM;
    float s = 0.f;
    #pragma unroll 8
    for (int i = 0; i < 64; ++i) {
      f4v vc = *(const f4v*)(cw + i * 4);
      f4v vg = *(const f4v*)(gate_w + i * 4);
      s += vc[0] * vg[0] + vc[1] * vg[1] + vc[2] * vg[2] + vc[3] * vg[3];
    }
    cgL[tid] = s;
    if (tid == 0) {
      float s2 = 0.f;
      for (int j = 0; j < DIM; ++j) s2 += cur_b[j] * gate_w[j];
      cbL[0] = s2 + gate_b[0];
    }
  }
  __syncthreads();

  // ---- wcur[p] = x[p]·cg + cb ----
  float* wp = (float*)(smem + EP_WP);    // [64][4]
  {
    const int row = tid & 63, sg = tid >> 6;
    const float* xr = xb + (size_t)(p0 + row) * DIM + sg * 64;
    const float* cgp = cgL + sg * 64;
    float sacc = 0.f;
    #pragma unroll
    for (int i = 0; i < 16; ++i) {
      f4v xv4 = *(const f4v*)(xr + i * 4);
      sacc += xv4[0] * cgp[i * 4] + xv4[1] * cgp[i * 4 + 1]
            + xv4[2] * cgp[i * 4 + 2] + xv4[3] * cgp[i * 4 + 3];
    }
    wp[row * 4 + sg] = sacc;
  }
  __syncthreads();
  float* wcS = (float*)(smem + EP_WP);   // [64], wave-0 own-slot overwrite
  if (tid < 64) {
    const float v = wp[tid * 4] + wp[tid * 4 + 1] + wp[tid * 4 + 2] + wp[tid * 4 + 3] + cbL[0];
    wcS[tid] = v;
  }
  __syncthreads();

  // ---- h = H_hist + mlp_b + wcur*x ; LN ----
  float s1l[2][4], s2l[2][4];
  #pragma unroll
  for (int a = 0; a < 2; ++a)
    #pragma unroll
    for (int r = 0; r < 4; ++r) { s1l[a][r] = 0.f; s2l[a][r] = 0.f; }
  #pragma unroll
  for (int a = 0; a < 2; ++a)
    #pragma unroll
    for (int i = 0; i < 8; ++i) {
      const int n = (i >> 1) * 64 + wc * 32 + (i & 1) * 16 + col16;
      const float mb = mlp_b[n];
      #pragma unroll
      for (int r = 0; r < 4; ++r) {
        const int row = rw + a * 16 + quad * 4 + r;
        const float xv = xb[(size_t)(p0 + row) * DIM + n];
        const float v = accH[a][i][r] + mb + wcS[row] * xv;
        accH[a][i][r] = v;
        s1l[a][r] += v;
        s2l[a][r] += v * v;
      }
    }
  #pragma unroll
  for (int a = 0; a < 2; ++a)
    #pragma unroll
    for (int r = 0; r < 4; ++r) {
      float v1 = s1l[a][r], v2 = s2l[a][r];
      v1 += __shfl_xor(v1, 1, 64); v2 += __shfl_xor(v2, 1, 64);
      v1 += __shfl_xor(v1, 2, 64); v2 += __shfl_xor(v2, 2, 64);
      v1 += __shfl_xor(v1, 4, 64); v2 += __shfl_xor(v2, 4, 64);
      v1 += __shfl_xor(v1, 8, 64); v2 += __shfl_xor(v2, 8, 64);
      s1l[a][r] = v1; s2l[a][r] = v2;
    }
  float* Ls = (float*)(smem + EP_LS);    // [2][64]
  float* Lq = (float*)(smem + EP_LQ);    // [2][64]
  if (col16 == 0) {
    #pragma unroll
    for (int a = 0; a < 2; ++a)
      #pragma unroll
      for (int r = 0; r < 4; ++r) {
        const int row = rw + a * 16 + quad * 4 + r;
        Ls[wc * 64 + row] = s1l[a][r];   // note: [2][64] flattened below
        Lq[wc * 64 + row] = s2l[a][r];
      }
  }
  __syncthreads();

  #pragma unroll
  for (int a = 0; a < 2; ++a) {
    float mean_[4], rstd_[4];
    #pragma unroll
    for (int r = 0; r < 4; ++r) {
      const int row = rw + a * 16 + quad * 4 + r;
      const float S1 = Ls[row] + Ls[64 + row];
      const float S2 = Lq[row] + Lq[64 + row];
      const float mean = S1 * (1.0f / 256.0f);
      const float var = S2 * (1.0f / 256.0f) - mean * mean;
      mean_[r] = mean;
      rstd_[r] = rsqrtf(fmaxf(var, 0.f) + 1e-5f);
    }
    #pragma unroll
    for (int i = 0; i < 8; ++i) {
      const int n = (i >> 1) * 64 + wc * 32 + (i & 1) * 16 + col16;
      const float g = ln_g[n];
      const float be = ln_b[n];
      #pragma unroll
      for (int r = 0; r < 4; ++r) {
        const int row = rw + a * 16 + quad * 4 + r;
        const float y = (accH[a][i][r] - mean_[r]) * rstd_[r] * g + be;
        out[((size_t)b * SEQ + p0 + row) * DIM + n] = y;
      }
    }
  }

  // ---- origin passthrough ----
  {
    const int row = tid >> 2, cs = (tid & 3) * 64;
    const float* src = xb + (size_t)(p0 + row) * DIM + cs;
    float* dst = out + ORIGIN_OFF + ((size_t)b * SEQ + p0 + row) * DIM + cs;
    #pragma unroll
    for (int j = 0; j < 16; ++j)
      *(f4v*)(dst + j * 4) = *(const f4v*)(src + j * 4);
  }
}

extern "C" void kernel_launch(void* const* d_in, const int* in_sizes, int n_in,
                              void* d_out, int out_size, void* d_ws, size_t ws_size,
                              hipStream_t stream) {
  const float* x      = (const float*)d_in[0];
  const float* mlp_w  = (const float*)d_in[1];
  const float* mlp_b  = (const float*)d_in[2];
  const float* his_w  = (const float*)d_in[3];
  const float* his_b  = (const float*)d_in[4];
  const float* cur_w  = (const float*)d_in[5];
  const float* cur_b  = (const float*)d_in[6];
  const float* wl_w   = (const float*)d_in[7];
  const float* wl_b   = (const float*)d_in[8];
  const float* gate_w = (const float*)d_in[9];
  const float* gate_b = (const float*)d_in[10];
  const float* ln_g   = (const float*)d_in[11];
  const float* ln_b   = (const float*)d_in[12];

  unsigned short* ws = (unsigned short*)d_ws;

  prep_all<<<dim3(4256), 256, 0, stream>>>(x, wl_w, his_w, mlp_w, ws);
  tfs_kernel<<<dim3(32, 32), 256, 0, stream>>>(
      x, mlp_b, his_b, cur_w, cur_b, wl_b, gate_w, gate_b,
      ln_g, ln_b, ws, (float*)d_out);
}

// Round 4
// 448.269 us; speedup vs baseline: 3.0572x; 3.0572x over previous
//
#include <hip/hip_runtime.h>
#include <hip/hip_bf16.h>

typedef __attribute__((ext_vector_type(8))) short s8v;
typedef __attribute__((ext_vector_type(4))) float f4v;
typedef __attribute__((ext_vector_type(4))) unsigned int u4v;

#define BATCH 32
#define SEQ   2048
#define DIM   256
#define ORIGIN_OFF ((size_t)BATCH * SEQ * DIM)

// ---- workspace layout (units: bf16 shorts) ----
// xT  [32][256][2048] : x transposed per batch, bf16, q-PERMUTED within each
//                       64-group: pos=32h+8quad+j holds q=32h+16(j>>2)+4quad+(j&3)
// wlT [2048 q][256 k] : wl_w^T bf16 (natural order)
// hisT/mlpT [256 n][256 k] bf16
#define XT_OFF  0ull
#define WL_OFF  16777216ull
#define HIS_OFF 17301504ull
#define MLP_OFF 17367040ull

// ---- LDS layout (bytes), total 131072 (1 block/CU, 8 waves) ----
// flash: bufK0 @0 (32768), bufK1 @32768, bufX0 @65536, bufX1 @98304
//        each [64 q][512B] / [256 d][128B], chunk-XOR bank swizzle
// prolog/epilog (aliased): Q/agg [128 p][528B] @0 (67584)
//        W-stage @98304 (32768); cg @69632, cb @70656, wp @70672, wcS @72720
#define BK0   0
#define BK1   32768
#define BX0   65536
#define BX1   98304
#define EP_CG 69632
#define EP_CB 70656
#define EP_WP 70672
#define EP_WC 72720

__device__ __forceinline__ unsigned short f2bf(float f) {
  __hip_bfloat16 h = __float2bfloat16(f);   // round-to-nearest-even
  return *reinterpret_cast<unsigned short*>(&h);
}
__device__ __forceinline__ f4v mfma16(s8v a, s8v b, f4v c) {
  return __builtin_amdgcn_mfma_f32_16x16x32_bf16(a, b, c, 0, 0, 0);
}
__device__ __forceinline__ unsigned int pk2(float lo, float hi) {
  return (unsigned int)f2bf(lo) | ((unsigned int)f2bf(hi) << 16);
}
// async global->LDS, 16B/lane; LDS dest = wave-uniform base + lane*16
__device__ __forceinline__ void dma16(const void* g, void* l) {
  __builtin_amdgcn_global_load_lds(
      (const __attribute__((address_space(1))) unsigned int*)g,
      (__attribute__((address_space(3))) unsigned int*)l, 16, 0, 0);
}

// ---------------- unified prep kernel ----------------
// 64x64 tile transpose f32 -> bf16 via LDS, chunk-XOR-swizzled.
// xT path additionally applies the q-permutation within each 64-group.
// grid.x = 4096 (xT) + 128 (wl) + 16 (his) + 16 (mlp) = 4256
__global__ __launch_bounds__(256) void prep_all(
    const float* __restrict__ x, const float* __restrict__ wl_w,
    const float* __restrict__ his_w, const float* __restrict__ mlp_w,
    unsigned short* __restrict__ ws)
{
  __shared__ unsigned short tile[64][72];   // 144B stride
  const int t = threadIdx.x;
  const int tb = blockIdx.x;
  const float* src; unsigned short* dst; int lds_, ldd_, r0, c0;
  bool isx = false;
  if (tb < 4096) {
    const int b = tb >> 7, rem = tb & 127;
    r0 = (rem >> 2) * 64;  c0 = (rem & 3) * 64;
    src = x + (size_t)b * SEQ * DIM;  lds_ = DIM;
    dst = ws + XT_OFF + (size_t)b * DIM * SEQ;  ldd_ = SEQ;
    isx = true;
  } else if (tb < 4224) {
    const int t2 = tb - 4096;
    r0 = (t2 >> 5) * 64;  c0 = (t2 & 31) * 64;
    src = wl_w;  lds_ = 2048;  dst = ws + WL_OFF;  ldd_ = 256;
  } else if (tb < 4240) {
    const int t2 = tb - 4224;
    r0 = (t2 >> 2) * 64;  c0 = (t2 & 3) * 64;
    src = his_w;  lds_ = 256;  dst = ws + HIS_OFF;  ldd_ = 256;
  } else {
    const int t2 = tb - 4240;
    r0 = (t2 >> 2) * 64;  c0 = (t2 & 3) * 64;
    src = mlp_w;  lds_ = 256;  dst = ws + MLP_OFF;  ldd_ = 256;
  }
  { // phase 1: coalesced row reads, 16B chunks at slot ch^(rr>>4)
    const int rr = t >> 2, cc = (t & 3) * 16;
    const float* s0 = src + (size_t)(r0 + rr) * lds_ + c0 + cc;
    f4v v0 = *(const f4v*)(s0);
    f4v v1 = *(const f4v*)(s0 + 4);
    f4v v2 = *(const f4v*)(s0 + 8);
    f4v v3 = *(const f4v*)(s0 + 12);
    u4v o0, o1;
    o0[0] = pk2(v0[0], v0[1]); o0[1] = pk2(v0[2], v0[3]);
    o0[2] = pk2(v1[0], v1[1]); o0[3] = pk2(v1[2], v1[3]);
    o1[0] = pk2(v2[0], v2[1]); o1[1] = pk2(v2[2], v2[3]);
    o1[2] = pk2(v3[0], v3[1]); o1[3] = pk2(v3[2], v3[3]);
    const int swz = rr >> 4;
    const int ch = cc >> 3;          // 0,2,4,6
    unsigned short* trow = &tile[rr][0];
    *(u4v*)(trow + ((ch ^ swz) << 3)) = o0;
    *(u4v*)(trow + (((ch + 1) ^ swz) << 3)) = o1;
  }
  __syncthreads();
  {
    const int cl = t >> 2, sg = t & 3;
    const int el = cl & 7;
    u4v o0, o1;
    if (isx) { // permuted content order
      #pragma unroll
      for (int m = 0; m < 8; ++m) {
        const int q = 32 * (sg >> 1) + 8 * (sg & 1)
                    + 16 * ((m >> 1) & 1) + 4 * (m >> 2) + 2 * (m & 1);
        const int chb = ((cl >> 3) ^ (q >> 4)) << 3;
        const unsigned int vv = (unsigned int)tile[q][chb + el]
                              | ((unsigned int)tile[q + 1][chb + el] << 16);
        if (m < 4) o0[m] = vv; else o1[m - 4] = vv;
      }
    } else {   // identity order
      const int chb = ((cl >> 3) ^ sg) << 3;
      #pragma unroll
      for (int j = 0; j < 4; ++j) {
        const int rA = sg * 16 + 2 * j;
        o0[j] = (unsigned int)tile[rA][chb + el]
              | ((unsigned int)tile[rA + 1][chb + el] << 16);
      }
      #pragma unroll
      for (int j = 0; j < 4; ++j) {
        const int rA = sg * 16 + 8 + 2 * j;
        o1[j] = (unsigned int)tile[rA][chb + el]
              | ((unsigned int)tile[rA + 1][chb + el] << 16);
      }
    }
    unsigned short* d0 = dst + (size_t)(c0 + cl) * ldd_ + r0 + sg * 16;
    *(u4v*)d0 = o0;
    *(u4v*)(d0 + 8) = o1;
  }
}

// ---------------- main kernel ----------------

// acc[st*4+nt] += A(regs af, own 16 p) @ Wt[n 256][k 256]; 4 DMA-staged
// stages of [64 n][512B] into BX1. n = (i>>2)*64 + (i&3)*16 + col16.
__device__ __forceinline__ void gemm_stage(
    const unsigned short* __restrict__ Wt, const s8v (&af)[8],
    f4v (&acc)[16], char* smem_, int wq, int lane, int col16, int quad, int x7)
{
  char* sW = smem_ + BX1;
  const int rsub = lane >> 5;
  const int c = lane & 31;
  for (int st = 0; st < 4; ++st) {
    if (st) __syncthreads();             // prior-stage reads drained
    #pragma unroll
    for (int j = 0; j < 4; ++j) {
      const int row = wq * 8 + 2 * j + rsub;
      dma16(Wt + (size_t)(st * 64 + row) * 256 + ((c ^ (row & 7)) << 3),
            sW + wq * 4096 + j * 1024);
    }
    __syncthreads();                     // DMA complete
    #pragma unroll
    for (int s = 0; s < 8; ++s) {
      const int co = ((s * 4 + quad) ^ x7) << 4;
      #pragma unroll
      for (int nt = 0; nt < 4; ++nt) {
        s8v bfr = *(const s8v*)(sW + (nt * 16 + col16) * 512 + co);
        acc[st * 4 + nt] = mfma16(af[s], bfr, acc[st * 4 + nt]);
      }
    }
  }
}

__global__ __launch_bounds__(512, 2)
void tfs_kernel(
    const float* __restrict__ x,
    const float* __restrict__ mlp_b,
    const float* __restrict__ his_b,
    const float* __restrict__ cur_w,
    const float* __restrict__ cur_b,
    const float* __restrict__ wl_b,
    const float* __restrict__ gate_w,
    const float* __restrict__ gate_b,
    const float* __restrict__ ln_g,
    const float* __restrict__ ln_b,
    const unsigned short* __restrict__ wsp,
    float* __restrict__ out)
{
  __shared__ __align__(16) char smem[131072];

  const int tid = threadIdx.x;
  const int lane = tid & 63;
  const int col16 = lane & 15;
  const int quad = lane >> 4;
  const int w = tid >> 6;                 // 0..7
  const int x7 = col16 & 7;
  const int wq = __builtin_amdgcn_readfirstlane(w);

  const int b = blockIdx.y;
  const int pidx = (blockIdx.x + b) & 15; // balance pidx across dispatch order
  const int p0 = pidx * 128;
  const int pw = p0 + w * 16;             // wave p-base
  const int pmax_qi = (p0 + 127) >> 6;

  const float* xb = x + (size_t)b * SEQ * DIM;
  const unsigned short* wlT  = wsp + WL_OFF;
  const unsigned short* hisT = wsp + HIS_OFF;
  const unsigned short* mlpT = wsp + MLP_OFF;
  const unsigned short* xTb  = wsp + XT_OFF + (size_t)b * DIM * SEQ;
  const f4v zero4 = {0.f, 0.f, 0.f, 0.f};

  // ---- x fragments (own 16 p-rows) direct from global, f32->bf16 ----
  s8v xf[8];
  {
    const float* srcx = xb + (size_t)(pw + col16) * DIM;
    #pragma unroll
    for (int s = 0; s < 8; ++s) {
      const int k0 = (s * 4 + quad) * 8;
      f4v v0 = *(const f4v*)(srcx + k0);
      f4v v1 = *(const f4v*)(srcx + k0 + 4);
      u4v o;
      o[0] = pk2(v0[0], v0[1]); o[1] = pk2(v0[2], v0[3]);
      o[2] = pk2(v1[0], v1[1]); o[3] = pk2(v1[2], v1[3]);
      xf[s] = *(s8v*)&o;
    }
  }

  // ---- Q = x @ his_w + his_b ----
  f4v accQ[16];
  #pragma unroll
  for (int i = 0; i < 16; ++i) accQ[i] = zero4;
  gemm_stage(hisT, xf, accQ, smem, wq, lane, col16, quad, x7);
  // writeback Q -> LDS @0 [128 p][528B]
  #pragma unroll
  for (int i = 0; i < 16; ++i) {
    const int n = (i >> 2) * 64 + (i & 3) * 16 + col16;
    const float bias = his_b[n];
    #pragma unroll
    for (int r = 0; r < 4; ++r) {
      const int row = w * 16 + quad * 4 + r;
      *(unsigned short*)(smem + row * 528 + n * 2) = f2bf(accQ[i][r] + bias);
    }
  }
  __syncthreads();                        // Q visible
  s8v qf[8];                              // qi-invariant Q fragments
  #pragma unroll
  for (int s = 0; s < 8; ++s)
    qf[s] = *(const s8v*)(smem + (w * 16 + col16) * 528 + (s * 4 + quad) * 16);
  __syncthreads();                        // qf reads done; regions free

  // ---- stage sK(0) -> BK0 and sXt(0) -> BX0 ----
  {
    const int rsub = lane >> 5, c = lane & 31;
    #pragma unroll
    for (int j = 0; j < 4; ++j) {
      const int row = wq * 8 + 2 * j + rsub;
      dma16(wlT + ((size_t)row << 8) + ((c ^ (row & 7)) << 3),
            smem + BK0 + wq * 4096 + j * 1024);
    }
    const int dsub = lane >> 3, cx = lane & 7;
    #pragma unroll
    for (int j = 0; j < 4; ++j) {
      const int d = wq * 32 + 8 * j + dsub;
      dma16(xTb + ((size_t)d << 11) + ((cx ^ dsub) << 3),
            smem + BX0 + wq * 4096 + j * 1024);
    }
  }
  __syncthreads();                        // tiles 0 ready

  // ---- flash loop: 1 barrier per qi, softmax wave-local ----
  f4v accO[16];
  #pragma unroll
  for (int dt = 0; dt < 16; ++dt) accO[dt] = zero4;
  float mrun = -1.0e30f, Zrun = 0.f;      // state for own p = pw + col16

  #pragma unroll 1
  for (int qi = 0; qi < 32; ++qi) {
    const int q0 = qi * 64;
    char* bK = smem + BK0 + ((qi & 1) << 15);
    char* bX = smem + BX0 + ((qi & 1) << 15);
    char* nK = smem + BK0 + ((~qi & 1) << 15);
    char* nX = smem + BX0 + ((~qi & 1) << 15);

    // prefetch qi+1 (drained for free at loop-end barrier)
    if (qi < 31) {
      const int rsub = lane >> 5, c = lane & 31;
      #pragma unroll
      for (int j = 0; j < 4; ++j) {
        const int row = wq * 8 + 2 * j + rsub;
        dma16(wlT + ((size_t)(q0 + 64 + row) << 8) + ((c ^ (row & 7)) << 3),
              nK + wq * 4096 + j * 1024);
      }
      if (qi + 1 <= pmax_qi) {
        const int dsub = lane >> 3, cx = lane & 7;
        #pragma unroll
        for (int j = 0; j < 4; ++j) {
          const int d = wq * 32 + 8 * j + dsub;
          dma16(xTb + ((size_t)d << 11) + (q0 + 64) + ((cx ^ dsub) << 3),
                nX + wq * 4096 + j * 1024);
        }
      }
    }

    // --- S^T = K @ Q : accST[t][r] = S[q=t*16+quad*4+r][p=pw+col16] ---
    f4v accST[4];
    accST[0] = zero4; accST[1] = zero4; accST[2] = zero4; accST[3] = zero4;
    #pragma unroll
    for (int s = 0; s < 8; ++s) {
      const int co = ((s * 4 + quad) ^ x7) << 4;
      #pragma unroll
      for (int t = 0; t < 4; ++t) {
        s8v kf = *(const s8v*)(bK + (t * 16 + col16) * 512 + co);
        accST[t] = mfma16(kf, qf[s], accST[t]);
      }
    }
    // + wl_b
    #pragma unroll
    for (int t = 0; t < 4; ++t) {
      const f4v wb = *(const f4v*)(wl_b + q0 + t * 16 + quad * 4);
      #pragma unroll
      for (int r = 0; r < 4; ++r) accST[t][r] += wb[r];
    }
    // row max for own p: in-lane 16 + cross-quad (2 shfl)
    float m01 = fmaxf(fmaxf(accST[0][0], accST[0][1]), fmaxf(accST[0][2], accST[0][3]));
    float m23 = fmaxf(fmaxf(accST[1][0], accST[1][1]), fmaxf(accST[1][2], accST[1][3]));
    float m45 = fmaxf(fmaxf(accST[2][0], accST[2][1]), fmaxf(accST[2][2], accST[2][3]));
    float m67 = fmaxf(fmaxf(accST[3][0], accST[3][1]), fmaxf(accST[3][2], accST[3][3]));
    float mt = fmaxf(fmaxf(m01, m23), fmaxf(m45, m67));
    mt = fmaxf(mt, __shfl_xor(mt, 16, 64));
    mt = fmaxf(mt, __shfl_xor(mt, 32, 64));
    const int grow = (mt > mrun) ? 1 : 0;
    const float mnew = fmaxf(mrun, mt);
    // P = exp(S - m), unmasked (denominator over all q)
    float Pv[4][4];
    #pragma unroll
    for (int t = 0; t < 4; ++t)
      #pragma unroll
      for (int r = 0; r < 4; ++r)
        Pv[t][r] = __expf(fminf(accST[t][r] - mnew, 0.f));
    // row sum: in-lane 16 + cross-quad
    float rs = 0.f;
    #pragma unroll
    for (int t = 0; t < 4; ++t)
      rs += (Pv[t][0] + Pv[t][1]) + (Pv[t][2] + Pv[t][3]);
    rs += __shfl_xor(rs, 16, 64);
    rs += __shfl_xor(rs, 32, 64);

    // rescale (wave-uniform skip when no row max grew: alpha == 1 exactly)
    if (__any(grow)) {
      const float alpha = __expf(fminf(mrun - mnew, 0.f));
      float aO[4];
      #pragma unroll
      for (int r = 0; r < 4; ++r) aO[r] = __shfl(alpha, quad * 4 + r, 64);
      #pragma unroll
      for (int dt = 0; dt < 16; ++dt)
        #pragma unroll
        for (int r = 0; r < 4; ++r) accO[dt][r] *= aO[r];
      Zrun = Zrun * alpha + rs;
    } else {
      Zrun += rs;
    }
    mrun = mnew;

    // --- PV (only waves with any unmasked q in this tile) ---
    if (q0 <= pw + 15) {
      const int lim = pw + col16 - q0;    // keep q <= lim
      float Pm[4][4];
      #pragma unroll
      for (int t = 0; t < 4; ++t)
        #pragma unroll
        for (int r = 0; r < 4; ++r) {
          const int q = t * 16 + quad * 4 + r;
          Pm[t][r] = (q <= lim) ? Pv[t][r] : 0.f;
        }
      #pragma unroll
      for (int h = 0; h < 2; ++h) {
        u4v pw4;
        pw4[0] = pk2(Pm[2 * h][0], Pm[2 * h][1]);
        pw4[1] = pk2(Pm[2 * h][2], Pm[2 * h][3]);
        pw4[2] = pk2(Pm[2 * h + 1][0], Pm[2 * h + 1][1]);
        pw4[3] = pk2(Pm[2 * h + 1][2], Pm[2 * h + 1][3]);
        s8v pa = *(s8v*)&pw4;             // A-frag in permuted-q order
        const int co = ((h * 4 + quad) ^ x7) << 4;
        #pragma unroll
        for (int dt = 0; dt < 16; ++dt) {
          const int d = dt * 16 + col16;
          s8v bv = *(const s8v*)(bX + d * 128 + co);
          accO[dt] = mfma16(pa, bv, accO[dt]);
        }
      }
    }
    __syncthreads();  // buffers turn over; prefetch DMA drained (no stall)
  } // qi

  // ---- epilogue: agg = O/Z -> LDS @0 (bf16, [128][528]) ----
  float invZO[4];
  #pragma unroll
  for (int r = 0; r < 4; ++r) {
    const float z = __shfl(Zrun, quad * 4 + r, 64);
    invZO[r] = 1.0f / fmaxf(z, 1e-30f);
  }
  #pragma unroll
  for (int dt = 0; dt < 16; ++dt) {
    const int d = dt * 16 + col16;
    #pragma unroll
    for (int r = 0; r < 4; ++r) {
      const int row = w * 16 + quad * 4 + r;
      *(unsigned short*)(smem + row * 528 + d * 2) = f2bf(accO[dt][r] * invZO[r]);
    }
  }
  __syncthreads();                        // agg visible
  s8v af[8];
  #pragma unroll
  for (int s = 0; s < 8; ++s)
    af[s] = *(const s8v*)(smem + (w * 16 + col16) * 528 + (s * 4 + quad) * 16);

  // ---- H_hist = agg @ mlp_w ----
  f4v accH[16];
  #pragma unroll
  for (int i = 0; i < 16; ++i) accH[i] = zero4;
  gemm_stage(mlpT, af, accH, smem, wq, lane, col16, quad, x7);

  // ---- cg[d] = cur_w[d,:]·gate_w ; cb ----
  float* cgL = (float*)(smem + EP_CG);
  float* cbL = (float*)(smem + EP_CB);
  if (tid < 256) {
    const float* cw = cur_w + (size_t)tid * DIM;
    float s = 0.f;
    #pragma unroll 8
    for (int i = 0; i < 64; ++i) {
      f4v vc = *(const f4v*)(cw + i * 4);
      f4v vg = *(const f4v*)(gate_w + i * 4);
      s += vc[0] * vg[0] + vc[1] * vg[1] + vc[2] * vg[2] + vc[3] * vg[3];
    }
    cgL[tid] = s;
    if (tid == 0) {
      float s2 = 0.f;
      for (int j = 0; j < DIM; ++j) s2 += cur_b[j] * gate_w[j];
      cbL[0] = s2 + gate_b[0];
    }
  }
  __syncthreads();

  // ---- wcur[p] = x[p]·cg + cb ----
  float* wp = (float*)(smem + EP_WP);     // [128][4]
  {
    const int row = tid >> 2, sg = tid & 3;
    const float* xr = xb + (size_t)(p0 + row) * DIM + sg * 64;
    const float* cgp = cgL + sg * 64;
    float sacc = 0.f;
    #pragma unroll
    for (int i = 0; i < 16; ++i) {
      f4v xv4 = *(const f4v*)(xr + i * 4);
      sacc += xv4[0] * cgp[i * 4] + xv4[1] * cgp[i * 4 + 1]
            + xv4[2] * cgp[i * 4 + 2] + xv4[3] * cgp[i * 4 + 3];
    }
    wp[row * 4 + sg] = sacc;
  }
  __syncthreads();
  float* wcS = (float*)(smem + EP_WC);    // [128] (separate region, no alias)
  if (tid < 128) {
    wcS[tid] = wp[tid * 4] + wp[tid * 4 + 1] + wp[tid * 4 + 2] + wp[tid * 4 + 3]
             + cbL[0];
  }
  __syncthreads();

  // ---- h = H_hist + mlp_b + wcur*x ; LN (wave-local reduction) ----
  float s1l[4], s2l[4];
  #pragma unroll
  for (int r = 0; r < 4; ++r) { s1l[r] = 0.f; s2l[r] = 0.f; }
  #pragma unroll
  for (int i = 0; i < 16; ++i) {
    const int n = (i >> 2) * 64 + (i & 3) * 16 + col16;
    const float mb = mlp_b[n];
    #pragma unroll
    for (int r = 0; r < 4; ++r) {
      const int row = w * 16 + quad * 4 + r;
      const float xv = xb[(size_t)(p0 + row) * DIM + n];
      const float v = accH[i][r] + mb + wcS[row] * xv;
      accH[i][r] = v;
      s1l[r] += v;
      s2l[r] += v * v;
    }
  }
  #pragma unroll
  for (int r = 0; r < 4; ++r) {
    float v1 = s1l[r], v2 = s2l[r];
    v1 += __shfl_xor(v1, 1, 64); v2 += __shfl_xor(v2, 1, 64);
    v1 += __shfl_xor(v1, 2, 64); v2 += __shfl_xor(v2, 2, 64);
    v1 += __shfl_xor(v1, 4, 64); v2 += __shfl_xor(v2, 4, 64);
    v1 += __shfl_xor(v1, 8, 64); v2 += __shfl_xor(v2, 8, 64);
    s1l[r] = v1; s2l[r] = v2;
  }
  float mean_[4], rstd_[4];
  #pragma unroll
  for (int r = 0; r < 4; ++r) {
    const float mean = s1l[r] * (1.0f / 256.0f);
    const float var = s2l[r] * (1.0f / 256.0f) - mean * mean;
    mean_[r] = mean;
    rstd_[r] = rsqrtf(fmaxf(var, 0.f) + 1e-5f);
  }
  #pragma unroll
  for (int i = 0; i < 16; ++i) {
    const int n = (i >> 2) * 64 + (i & 3) * 16 + col16;
    const float g = ln_g[n];
    const float be = ln_b[n];
    #pragma unroll
    for (int r = 0; r < 4; ++r) {
      const int row = w * 16 + quad * 4 + r;
      const float y = (accH[i][r] - mean_[r]) * rstd_[r] * g + be;
      out[((size_t)b * SEQ + p0 + row) * DIM + n] = y;
    }
  }

  // ---- origin passthrough ----
  {
    const int row = tid >> 2, cs = (tid & 3) * 64;
    const float* src = xb + (size_t)(p0 + row) * DIM + cs;
    float* dst = out + ORIGIN_OFF + ((size_t)b * SEQ + p0 + row) * DIM + cs;
    #pragma unroll
    for (int j = 0; j < 16; ++j)
      *(f4v*)(dst + j * 4) = *(const f4v*)(src + j * 4);
  }
}

extern "C" void kernel_launch(void* const* d_in, const int* in_sizes, int n_in,
                              void* d_out, int out_size, void* d_ws, size_t ws_size,
                              hipStream_t stream) {
  const float* x      = (const float*)d_in[0];
  const float* mlp_w  = (const float*)d_in[1];
  const float* mlp_b  = (const float*)d_in[2];
  const float* his_w  = (const float*)d_in[3];
  const float* his_b  = (const float*)d_in[4];
  const float* cur_w  = (const float*)d_in[5];
  const float* cur_b  = (const float*)d_in[6];
  const float* wl_w   = (const float*)d_in[7];
  const float* wl_b   = (const float*)d_in[8];
  const float* gate_w = (const float*)d_in[9];
  const float* gate_b = (const float*)d_in[10];
  const float* ln_g   = (const float*)d_in[11];
  const float* ln_b   = (const float*)d_in[12];

  unsigned short* ws = (unsigned short*)d_ws;

  prep_all<<<dim3(4256), 256, 0, stream>>>(x, wl_w, his_w, mlp_w, ws);
  tfs_kernel<<<dim3(16, 32), 512, 0, stream>>>(
      x, mlp_b, his_b, cur_w, cur_b, wl_b, gate_w, gate_b,
      ln_g, ln_b, ws, (float*)d_out);
}